// Round 1
// 249.480 us; speedup vs baseline: 1.0000x; 1.0000x over previous
//
#include <hip/hip_runtime.h>
#include <hip/hip_bf16.h>
#include <stdint.h>

// Problem constants (match reference)
#define NN 50000      // nodes
#define NE 800000     // edges
#define NL 100000     // label edges
#define SLOTS 64      // padded-CSR slots/node. deg~Poisson(16); P(deg>64)~1e-13.

// Bucketed CSR build (R7: direct scatter was line-bound)
#define NB 196        // dst-range buckets: bucket = dst >> 8 (256 nodes each)
#define BSH 8
#define BCAP 5376     // edges/bucket capacity; mean 4082 -> +20 sigma

typedef __attribute__((ext_vector_type(8))) short bf16x8;   // MFMA A/B frag
typedef __attribute__((ext_vector_type(4))) float f32x4;    // MFMA C/D frag
typedef __attribute__((ext_vector_type(4))) unsigned int u32x4;

__device__ __forceinline__ float asf(unsigned int u) {
    union { unsigned int i; float f; } c; c.i = u; return c.f;
}
__device__ __forceinline__ float bflo(unsigned int x) { return asf(x << 16); }
__device__ __forceinline__ float bfhi(unsigned int x) { return asf(x & 0xffff0000u); }
__device__ __forceinline__ unsigned short f2bf(float f) {
    union { float f; unsigned int i; } c; c.f = f;
    unsigned int u = c.i + (0x7fffu + ((c.i >> 16) & 1u));
    return (unsigned short)(u >> 16);
}

// ---- P0: W transpose+convert to bf16 Wt[n][k]; zero bucket cursors ----
__global__ void k_wprep(const float* __restrict__ W1, const float* __restrict__ W2,
                        const float* __restrict__ W3, unsigned short* __restrict__ Wt,
                        int* __restrict__ cursor) {
    int idx = blockIdx.x * 256 + threadIdx.x;   // grid exactly 160
    if (idx < NB) cursor[idx] = 0;
    const float* W; unsigned short* O; int base, Mloc;
    if (idx < 16384)      { W = W1; O = Wt;         base = idx;         Mloc = 128; }
    else if (idx < 32768) { W = W2; O = Wt + 16384; base = idx - 16384; Mloc = 128; }
    else                  { W = W3; O = Wt + 32768; base = idx - 32768; Mloc = 64;  }
    int n = base >> 7, k = base & 127;
    O[base] = f2bf(W[k * Mloc + n]);
}

// ---- P1: bin edges by dst range (LDS histogram -> packed NT writes) ----
// R13: cache packed edges in LDS during pass 1 -> pass 2 reads LDS, not global.
__global__ __launch_bounds__(256) void k_bin(
        const int* __restrict__ src, const int* __restrict__ dst,
        int* __restrict__ cursor, unsigned int* __restrict__ binbuf) {
    __shared__ int hcnt[NB];
    __shared__ int hbase[NB];
    __shared__ unsigned int epk[2048];
    int tid = threadIdx.x;
    if (tid < NB) hcnt[tid] = 0;
    __syncthreads();
    int e0 = blockIdx.x * 2048;                 // grid exactly 391
    int e1 = min(e0 + 2048, NE);
    for (int e = e0 + tid; e < e1; e += 256) {
        int d = dst[e], s = src[e];
        atomicAdd(&hcnt[d >> BSH], 1);
        epk[e - e0] = (unsigned int)s | ((unsigned int)d << 16);
    }
    __syncthreads();
    if (tid < NB) { hbase[tid] = atomicAdd(&cursor[tid], hcnt[tid]); hcnt[tid] = 0; }
    __syncthreads();
    for (int e = e0 + tid; e < e1; e += 256) {
        unsigned int pk = epk[e - e0];
        int b = (int)(pk >> 16) >> BSH;
        int p = hbase[b] + atomicAdd(&hcnt[b], 1);
        if (p < BCAP)
            __builtin_nontemporal_store(pk, &binbuf[(size_t)b * BCAP + p]);
    }
}

// ---- P2: per-bucket CSR build in LDS + coalesced flush ----
__global__ __launch_bounds__(256) void k_csr(
        const unsigned int* __restrict__ binbuf, const int* __restrict__ cursor,
        int* __restrict__ deg, unsigned short* __restrict__ colp) {
    __shared__ unsigned short lcol[256 * SLOTS];   // 32 KB
    __shared__ int ldeg[256];
    int tid = threadIdx.x;
    int blk = blockIdx.x;                          // grid exactly NB
    int base = blk << BSH;
    int nNodes = min(256, NN - base);
    ldeg[tid] = 0;
    __syncthreads();
    int cnt = min(cursor[blk], BCAP);
    for (int e = tid; e < cnt; e += 256) {
        unsigned int pk = __builtin_nontemporal_load(&binbuf[(size_t)blk * BCAP + e]);
        int d = (int)(pk >> 16) - base;
        int p = atomicAdd(&ldeg[d], 1);
        if (p < SLOTS) lcol[d * SLOTS + p] = (unsigned short)(pk & 0xffffu);
    }
    __syncthreads();
    if (tid < nNodes) deg[base + tid] = ldeg[tid];
    u32x4* gout = (u32x4*)(colp + (size_t)base * SLOTS);
    const u32x4* lin = (const u32x4*)lcol;
    for (int i = tid; i < nNodes * 8; i += 256) gout[i] = lin[i];
}

// ---- layer-1 GEMM: x (fp32) -> bufH. Zero LDS/barriers (R7 form) ----
// Outb[i,j] = bf16( rsqrt(deg[i]+1) * sum_k x[i,k]*W[k,j] ), K=128, M=128.
// C/D (m89-verified): col=lane&15, row=quad*4+reg.
__global__ __launch_bounds__(256) void k_gemm1(
        const float* __restrict__ A, const unsigned short* __restrict__ Wt,
        const int* __restrict__ deg, unsigned short* __restrict__ Outb, int N) {
    constexpr int K = 128;
    constexpr int NT = 8;
    int tid = threadIdx.x;
    int lane = tid & 63, wave = tid >> 6;
    int m = lane & 15, quad = lane >> 4;
    int rowA = blockIdx.x * 64 + wave * 16 + m;    // grid exactly 782
    int rA = min(rowA, N - 1);

    bf16x8 afr[4];
    const float* p = A + (size_t)rA * K + quad * 8;
#pragma unroll
    for (int s = 0; s < 4; ++s) {
        float4 lo = *(const float4*)(p + s * 32);
        float4 hi = *(const float4*)(p + s * 32 + 4);
        bf16x8 r;
        r[0] = (short)f2bf(lo.x); r[1] = (short)f2bf(lo.y);
        r[2] = (short)f2bf(lo.z); r[3] = (short)f2bf(lo.w);
        r[4] = (short)f2bf(hi.x); r[5] = (short)f2bf(hi.y);
        r[6] = (short)f2bf(hi.z); r[7] = (short)f2bf(hi.w);
        afr[s] = r;
    }

    f32x4 acc[NT];
#pragma unroll
    for (int t = 0; t < NT; ++t) { acc[t][0] = 0.f; acc[t][1] = 0.f; acc[t][2] = 0.f; acc[t][3] = 0.f; }
#pragma unroll
    for (int t = 0; t < NT; ++t) {
        const unsigned short* wp = Wt + (size_t)(t * 16 + m) * K + quad * 8;
#pragma unroll
        for (int s = 0; s < 4; ++s) {
            bf16x8 bfr = *(const bf16x8*)(wp + s * 32);
            acc[t] = __builtin_amdgcn_mfma_f32_16x16x32_bf16(afr[s], bfr, acc[t], 0, 0, 0);
        }
    }

    int outRowBase = blockIdx.x * 64 + wave * 16 + quad * 4;
    float di[4];
#pragma unroll
    for (int i = 0; i < 4; ++i) di[i] = rsqrtf((float)deg[min(outRowBase + i, N - 1)] + 1.0f);
#pragma unroll
    for (int t = 0; t < NT; ++t)
#pragma unroll
        for (int i = 0; i < 4; ++i) {
            int rr = outRowBase + i;
            if (rr < N) Outb[(size_t)rr * 128 + t * 16 + m] = f2bf(acc[t][i] * di[i]);
        }
}

// ---- FUSED agg+gemm (R13 gather rewrite) ----
// Gather phase: wave split into 4 groups of 16 lanes; group g, lane c=lane&15
// owns dims [c*8, c*8+8). One dwordx4 load = 4 neighbor rows per instruction
// (vs 1 row per instruction before), and loads are exec-PREDICATED on
// j+g < cnt so exactly deg rows are fetched (old code fetched ceil(deg/8)*8,
// ~27% masked row-0 spam). Partial sums reduced across groups via shfl_xor
// 16/32 (fp32 reassociation only). Group 0 applies dinv/bias/relu and writes
// the 16B bf16 slice into As. GEMM phase unchanged (As stride 132->136 so
// all LDS accesses are 16B-aligned).
template <int M_>
__global__ __launch_bounds__(256) void k_agg_gemm(
        const unsigned short* __restrict__ hs, const int* __restrict__ deg,
        const unsigned short* __restrict__ colp, const float* __restrict__ bias,
        const unsigned short* __restrict__ Wt, unsigned short* __restrict__ Outb) {
    constexpr int K = 128;          // agg feature width and gemm K
    constexpr int NT = M_ / 64;     // col tiles per wave: 128->2, 64->1
    __shared__ __align__(16) unsigned short As[16][136];
    int tid = threadIdx.x;
    int lane = tid & 63, wave = tid >> 6;
    int tileBase = blockIdx.x * 16;
    int g = lane >> 4, c = lane & 15;
    const unsigned short* hc = hs + c * 8;

    // per-lane bias slice (used by group 0 at write-out)
    float bv[8];
    {
        const float4* bp = (const float4*)(bias + c * 8);
        float4 b0 = bp[0], b1 = bp[1];
        bv[0] = b0.x; bv[1] = b0.y; bv[2] = b0.z; bv[3] = b0.w;
        bv[4] = b1.x; bv[5] = b1.y; bv[6] = b1.z; bv[7] = b1.w;
    }

    // ---- agg phase: wave aggregates rows wave*4 .. wave*4+3 ----
#pragma unroll
    for (int t = 0; t < 4; ++t) {
        int r = wave * 4 + t;
        int node = tileBase + r;
        int cnt = min(deg[node], SLOTS);
        int myIdx = (lane < cnt) ? (int)colp[(size_t)node * SLOTS + lane] : 0;

        float acc[8];
        {
            u32x4 v = {0, 0, 0, 0};
            if (g == 0) v = *(const u32x4*)(hc + (size_t)node * K);   // self term
#pragma unroll
            for (int k = 0; k < 4; ++k) { acc[2 * k] = bflo(v[k]); acc[2 * k + 1] = bfhi(v[k]); }
        }
        for (int j = 0; j < cnt; j += 8) {
            int i0 = __shfl(myIdx, j + g, 64);        // j+g     <= 63, no wrap
            int i1 = __shfl(myIdx, j + 4 + g, 64);    // j+4+g   <= 63, no wrap
            u32x4 v0 = {0, 0, 0, 0}, v1 = {0, 0, 0, 0};
            if (j + g < cnt)     v0 = *(const u32x4*)(hc + (size_t)i0 * K);
            if (j + 4 + g < cnt) v1 = *(const u32x4*)(hc + (size_t)i1 * K);
#pragma unroll
            for (int k = 0; k < 4; ++k) {
                acc[2 * k]     += bflo(v0[k]) + bflo(v1[k]);
                acc[2 * k + 1] += bfhi(v0[k]) + bfhi(v1[k]);
            }
        }
        // cross-group reduce: groups {0,1,2,3} hold partial sums of same dims
#pragma unroll
        for (int k = 0; k < 8; ++k) {
            acc[k] += __shfl_xor(acc[k], 16, 64);
            acc[k] += __shfl_xor(acc[k], 32, 64);
        }
        if (g == 0) {
            float di = rsqrtf((float)deg[node] + 1.0f);
            u32x4 pv;
#pragma unroll
            for (int k = 0; k < 4; ++k) {
                float o0 = fmaxf(di * acc[2 * k]     + bv[2 * k],     0.f);
                float o1 = fmaxf(di * acc[2 * k + 1] + bv[2 * k + 1], 0.f);
                pv[k] = (unsigned int)f2bf(o0) | ((unsigned int)f2bf(o1) << 16);
            }
            *(u32x4*)&As[r][c * 8] = pv;   // 16B aligned: 136*2*r % 16 == 0
        }
    }
    __syncthreads();

    // ---- gemm phase: 16 rows x M_ cols from LDS A-tile ----
    int m = lane & 15, quad = lane >> 4;
    bf16x8 afr[4];
#pragma unroll
    for (int s = 0; s < 4; ++s)
        afr[s] = *(const bf16x8*)&As[m][s * 32 + quad * 8];

    f32x4 gacc[NT];
#pragma unroll
    for (int t = 0; t < NT; ++t) { gacc[t][0] = 0.f; gacc[t][1] = 0.f; gacc[t][2] = 0.f; gacc[t][3] = 0.f; }
#pragma unroll
    for (int t = 0; t < NT; ++t) {
        int ct = wave * NT + t;     // col tile 0..M_/16-1
        const unsigned short* wp = Wt + (size_t)(ct * 16 + m) * K + quad * 8;
#pragma unroll
        for (int s = 0; s < 4; ++s) {
            bf16x8 bfr = *(const bf16x8*)(wp + s * 32);
            gacc[t] = __builtin_amdgcn_mfma_f32_16x16x32_bf16(afr[s], bfr, gacc[t], 0, 0, 0);
        }
    }

    int rowBase = tileBase + quad * 4;
    float di[4];
#pragma unroll
    for (int i = 0; i < 4; ++i) di[i] = rsqrtf((float)deg[rowBase + i] + 1.0f);
#pragma unroll
    for (int t = 0; t < NT; ++t) {
        int ct = wave * NT + t;
#pragma unroll
        for (int i = 0; i < 4; ++i)
            Outb[(size_t)(rowBase + i) * M_ + ct * 16 + m] = f2bf(gacc[t][i] * di[i]);
    }
}

// ---- final aggregation (F=64, no relu) -> z (bf16) ----
// R13: 8 groups of 8 lanes; one predicated dwordx4 load = 8 neighbor rows.
__global__ __launch_bounds__(256) void k_agg64(
        const unsigned short* __restrict__ hs, const int* __restrict__ deg,
        const unsigned short* __restrict__ colp, const float* __restrict__ bias,
        unsigned short* __restrict__ out, int n) {
    int tid = threadIdx.x;
    int wave = tid >> 6, lane = tid & 63;
    int node = blockIdx.x * 4 + wave;               // grid exactly 12500
    int g = lane >> 3, c = lane & 7;
    const unsigned short* hc = hs + c * 8;

    int cnt = min(deg[node], SLOTS);
    int myIdx = (lane < cnt) ? (int)colp[(size_t)node * SLOTS + lane] : 0;

    float acc[8];
    {
        u32x4 v = {0, 0, 0, 0};
        if (g == 0) v = *(const u32x4*)(hc + (size_t)node * 64);   // self term
#pragma unroll
        for (int k = 0; k < 4; ++k) { acc[2 * k] = bflo(v[k]); acc[2 * k + 1] = bfhi(v[k]); }
    }
    for (int j = 0; j < cnt; j += 16) {
        int i0 = __shfl(myIdx, j + g, 64);          // j+g   <= 55+... <= 63
        int i1 = __shfl(myIdx, j + 8 + g, 64);      // j+8+g <= 63
        u32x4 v0 = {0, 0, 0, 0}, v1 = {0, 0, 0, 0};
        if (j + g < cnt)     v0 = *(const u32x4*)(hc + (size_t)i0 * 64);
        if (j + 8 + g < cnt) v1 = *(const u32x4*)(hc + (size_t)i1 * 64);
#pragma unroll
        for (int k = 0; k < 4; ++k) {
            acc[2 * k]     += bflo(v0[k]) + bflo(v1[k]);
            acc[2 * k + 1] += bfhi(v0[k]) + bfhi(v1[k]);
        }
    }
#pragma unroll
    for (int k = 0; k < 8; ++k) {
        acc[k] += __shfl_xor(acc[k], 8, 64);
        acc[k] += __shfl_xor(acc[k], 16, 64);
        acc[k] += __shfl_xor(acc[k], 32, 64);
    }
    if (g == 0) {
        float di = rsqrtf((float)deg[node] + 1.0f);
        const float4* bp = (const float4*)(bias + c * 8);
        float4 b0 = bp[0], b1 = bp[1];
        float bb[8] = {b0.x, b0.y, b0.z, b0.w, b1.x, b1.y, b1.z, b1.w};
        u32x4 pv;
#pragma unroll
        for (int k = 0; k < 4; ++k) {
            float o0 = di * acc[2 * k]     + bb[2 * k];
            float o1 = di * acc[2 * k + 1] + bb[2 * k + 1];
            pv[k] = (unsigned int)f2bf(o0) | ((unsigned int)f2bf(o1) << 16);
        }
        *(u32x4*)(out + (size_t)node * 64 + c * 8) = pv;
    }
}

// ---- decode: out[e] = dot(z[ls[e]], z[ld[e]]) over 64 dims, z bf16 ----
// R13: 4 edges per wave. 8 lanes x 16B cover one 64-dim row; groups g=0..7
// map to (edge = g>>1, endpoint = g&1). shfl_xor(8) swaps endpoints so each
// lane multiplies its 8 dims; 3-step xor reduce within the 8-lane group.
__global__ __launch_bounds__(256) void k_decode(
        const unsigned short* __restrict__ z, const int* __restrict__ ls,
        const int* __restrict__ ld, float* __restrict__ out, int nl) {
    int tid = threadIdx.x;
    int lane = tid & 63, wave = tid >> 6;
    int g = lane >> 3, c = lane & 7;
    int e = (blockIdx.x * 4 + wave) * 4 + (g >> 1);   // grid exactly 6250
    int row = (g & 1) ? ld[e] : ls[e];
    u32x4 v = *(const u32x4*)(z + (size_t)row * 64 + c * 8);
    u32x4 w;
#pragma unroll
    for (int k = 0; k < 4; ++k) w[k] = (unsigned int)__shfl_xor((int)v[k], 8, 64);
    float p = 0.f;
#pragma unroll
    for (int k = 0; k < 4; ++k)
        p += bflo(v[k]) * bflo(w[k]) + bfhi(v[k]) * bfhi(w[k]);
    p += __shfl_xor(p, 1, 64);
    p += __shfl_xor(p, 2, 64);
    p += __shfl_xor(p, 4, 64);
    if ((lane & 15) == 0) out[e] = p;   // lane in {0,16,32,48}: g even, c==0
}

// ================= launcher =================

static inline size_t align256(size_t x) { return (x + 255) & ~(size_t)255; }

extern "C" void kernel_launch(void* const* d_in, const int* in_sizes, int n_in,
                              void* d_out, int out_size, void* d_ws, size_t ws_size,
                              hipStream_t stream) {
    const float* x  = (const float*)d_in[0];
    const int*   ei = (const int*)d_in[1];    // [2][NE]: row0=src, row1=dst
    const int*   li = (const int*)d_in[2];    // [2][NL]
    const float* W1 = (const float*)d_in[3];
    const float* b1 = (const float*)d_in[4];
    const float* W2 = (const float*)d_in[5];
    const float* b2 = (const float*)d_in[6];
    const float* W3 = (const float*)d_in[7];
    const float* b3 = (const float*)d_in[8];
    float* out = (float*)d_out;

    const int* src = ei;
    const int* dst = ei + NE;
    const int* ls = li;
    const int* ld = li + NL;

    // workspace carve-up (~37 MB)
    char* ws = (char*)d_ws;
    size_t off = 0;
    int* deg    = (int*)(ws + off); off += align256(NN * 4);
    int* cursor = (int*)(ws + off); off += align256(NB * 4);
    unsigned int* binbuf = (unsigned int*)(ws + off); off += align256((size_t)NB * BCAP * 4);
    unsigned short* colp = (unsigned short*)(ws + off); off += align256((size_t)NN * SLOTS * 2);
    unsigned short* Wtb  = (unsigned short*)(ws + off); off += align256(40960 * 2);
    unsigned short* bufA = (unsigned short*)(ws + off); off += align256((size_t)NN * 128 * 2);
    unsigned short* bufB = (unsigned short*)(ws + off); off += align256((size_t)NN * 128 * 2);
    unsigned short* bufZ = (unsigned short*)(ws + off); off += align256((size_t)NN * 64 * 2);

    // ---- CSR build + W prep ----
    k_wprep<<<160, 256, 0, stream>>>(W1, W2, W3, Wtb, cursor);
    k_bin<<<391, 256, 0, stream>>>(src, dst, cursor, binbuf);
    k_csr<<<NB, 256, 0, stream>>>(binbuf, cursor, deg, colp);

    // ---- layer 1 GEMM: x -> bufA (h1 = dinv * x@W1, bf16) ----
    k_gemm1<<<782, 256, 0, stream>>>(x, Wtb, deg, bufA, NN);
    // ---- fused agg1(+b1,relu) + gemm2: bufA -> bufB (h2) ----
    k_agg_gemm<128><<<3125, 256, 0, stream>>>(bufA, deg, colp, b1, Wtb + 16384, bufB);
    // ---- fused agg2(+b2,relu) + gemm3: bufB -> bufA (h3, 64-wide) ----
    k_agg_gemm<64><<<3125, 256, 0, stream>>>(bufB, deg, colp, b2, Wtb + 32768, bufA);
    // ---- agg3(+b3, no relu): bufA -> bufZ (z) ----
    k_agg64<<<12500, 256, 0, stream>>>(bufA, deg, colp, b3, bufZ, NN);
    // ---- decode ----
    k_decode<<<6250, 256, 0, stream>>>(bufZ, ls, ld, out, NL);
}

// Round 2
// 240.561 us; speedup vs baseline: 1.0371x; 1.0371x over previous
//
#include <hip/hip_runtime.h>
#include <hip/hip_bf16.h>
#include <stdint.h>

// Problem constants (match reference)
#define NN 50000      // nodes
#define NE 800000     // edges
#define NL 100000     // label edges
#define SLOTS 64      // padded-CSR slots/node. deg~Poisson(16); P(deg>64)~1e-13.

// Bucketed CSR build (R7: direct scatter was line-bound)
#define NB 196        // dst-range buckets: bucket = dst >> 8 (256 nodes each)
#define BSH 8
#define BCAP 5376     // edges/bucket capacity; mean 4082 -> +20 sigma

typedef __attribute__((ext_vector_type(8))) short bf16x8;   // MFMA A/B frag
typedef __attribute__((ext_vector_type(4))) float f32x4;    // MFMA C/D frag
typedef __attribute__((ext_vector_type(4))) unsigned int u32x4;
typedef __attribute__((ext_vector_type(8))) unsigned short u16x8;

__device__ __forceinline__ float asf(unsigned int u) {
    union { unsigned int i; float f; } c; c.i = u; return c.f;
}
__device__ __forceinline__ float bflo(unsigned int x) { return asf(x << 16); }
__device__ __forceinline__ float bfhi(unsigned int x) { return asf(x & 0xffff0000u); }
__device__ __forceinline__ unsigned short f2bf(float f) {
    union { float f; unsigned int i; } c; c.f = f;
    unsigned int u = c.i + (0x7fffu + ((c.i >> 16) & 1u));
    return (unsigned short)(u >> 16);
}

// ---- P0: W transpose+convert to bf16 Wt[n][k]; zero bucket cursors ----
__global__ void k_wprep(const float* __restrict__ W1, const float* __restrict__ W2,
                        const float* __restrict__ W3, unsigned short* __restrict__ Wt,
                        int* __restrict__ cursor) {
    int idx = blockIdx.x * 256 + threadIdx.x;   // grid exactly 160
    if (idx < NB) cursor[idx] = 0;
    const float* W; unsigned short* O; int base, Mloc;
    if (idx < 16384)      { W = W1; O = Wt;         base = idx;         Mloc = 128; }
    else if (idx < 32768) { W = W2; O = Wt + 16384; base = idx - 16384; Mloc = 128; }
    else                  { W = W3; O = Wt + 32768; base = idx - 32768; Mloc = 64;  }
    int n = base >> 7, k = base & 127;
    O[base] = f2bf(W[k * Mloc + n]);
}

// ---- P1: bin edges by dst range (LDS histogram -> packed NT writes) ----
__global__ __launch_bounds__(256) void k_bin(
        const int* __restrict__ src, const int* __restrict__ dst,
        int* __restrict__ cursor, unsigned int* __restrict__ binbuf) {
    __shared__ int hcnt[NB];
    __shared__ int hbase[NB];
    __shared__ unsigned int epk[2048];
    int tid = threadIdx.x;
    if (tid < NB) hcnt[tid] = 0;
    __syncthreads();
    int e0 = blockIdx.x * 2048;                 // grid exactly 391
    int e1 = min(e0 + 2048, NE);
    for (int e = e0 + tid; e < e1; e += 256) {
        int d = dst[e], s = src[e];
        atomicAdd(&hcnt[d >> BSH], 1);
        epk[e - e0] = (unsigned int)s | ((unsigned int)d << 16);
    }
    __syncthreads();
    if (tid < NB) { hbase[tid] = atomicAdd(&cursor[tid], hcnt[tid]); hcnt[tid] = 0; }
    __syncthreads();
    for (int e = e0 + tid; e < e1; e += 256) {
        unsigned int pk = epk[e - e0];
        int b = (int)(pk >> 16) >> BSH;
        int p = hbase[b] + atomicAdd(&hcnt[b], 1);
        if (p < BCAP)
            __builtin_nontemporal_store(pk, &binbuf[(size_t)b * BCAP + p]);
    }
}

// ---- P2: per-bucket CSR build in LDS + coalesced flush ----
// R14: lcol is ZEROED first -> pad slots hold index 0. The gather kernels now
// read pad slots unconditionally (mask applied to the VALUE, not the load),
// so pad indices must be valid (row 0, L1-hot).
__global__ __launch_bounds__(256) void k_csr(
        const unsigned int* __restrict__ binbuf, const int* __restrict__ cursor,
        int* __restrict__ deg, unsigned short* __restrict__ colp) {
    __shared__ unsigned short lcol[256 * SLOTS];   // 32 KB
    __shared__ int ldeg[256];
    int tid = threadIdx.x;
    int blk = blockIdx.x;                          // grid exactly NB
    int base = blk << BSH;
    int nNodes = min(256, NN - base);
    ldeg[tid] = 0;
    u32x4* lz = (u32x4*)lcol;
#pragma unroll
    for (int i = 0; i < 8; ++i) lz[i * 256 + tid] = (u32x4){0, 0, 0, 0};
    __syncthreads();
    int cnt = min(cursor[blk], BCAP);
    for (int e = tid; e < cnt; e += 256) {
        unsigned int pk = __builtin_nontemporal_load(&binbuf[(size_t)blk * BCAP + e]);
        int d = (int)(pk >> 16) - base;
        int p = atomicAdd(&ldeg[d], 1);
        if (p < SLOTS) lcol[d * SLOTS + p] = (unsigned short)(pk & 0xffffu);
    }
    __syncthreads();
    if (tid < nNodes) deg[base + tid] = ldeg[tid];
    u32x4* gout = (u32x4*)(colp + (size_t)base * SLOTS);
    const u32x4* lin = (const u32x4*)lcol;
    for (int i = tid; i < nNodes * 8; i += 256) gout[i] = lin[i];
}

// ---- layer-1 GEMM: x (fp32) -> bufH. Zero LDS/barriers (R7 form) ----
__global__ __launch_bounds__(256) void k_gemm1(
        const float* __restrict__ A, const unsigned short* __restrict__ Wt,
        const int* __restrict__ deg, unsigned short* __restrict__ Outb, int N) {
    constexpr int K = 128;
    constexpr int NT = 8;
    int tid = threadIdx.x;
    int lane = tid & 63, wave = tid >> 6;
    int m = lane & 15, quad = lane >> 4;
    int rowA = blockIdx.x * 64 + wave * 16 + m;    // grid exactly 782
    int rA = min(rowA, N - 1);

    bf16x8 afr[4];
    const float* p = A + (size_t)rA * K + quad * 8;
#pragma unroll
    for (int s = 0; s < 4; ++s) {
        float4 lo = *(const float4*)(p + s * 32);
        float4 hi = *(const float4*)(p + s * 32 + 4);
        bf16x8 r;
        r[0] = (short)f2bf(lo.x); r[1] = (short)f2bf(lo.y);
        r[2] = (short)f2bf(lo.z); r[3] = (short)f2bf(lo.w);
        r[4] = (short)f2bf(hi.x); r[5] = (short)f2bf(hi.y);
        r[6] = (short)f2bf(hi.z); r[7] = (short)f2bf(hi.w);
        afr[s] = r;
    }

    f32x4 acc[NT];
#pragma unroll
    for (int t = 0; t < NT; ++t) { acc[t][0] = 0.f; acc[t][1] = 0.f; acc[t][2] = 0.f; acc[t][3] = 0.f; }
#pragma unroll
    for (int t = 0; t < NT; ++t) {
        const unsigned short* wp = Wt + (size_t)(t * 16 + m) * K + quad * 8;
#pragma unroll
        for (int s = 0; s < 4; ++s) {
            bf16x8 bfr = *(const bf16x8*)(wp + s * 32);
            acc[t] = __builtin_amdgcn_mfma_f32_16x16x32_bf16(afr[s], bfr, acc[t], 0, 0, 0);
        }
    }

    int outRowBase = blockIdx.x * 64 + wave * 16 + quad * 4;
    float di[4];
#pragma unroll
    for (int i = 0; i < 4; ++i) di[i] = rsqrtf((float)deg[min(outRowBase + i, N - 1)] + 1.0f);
#pragma unroll
    for (int t = 0; t < NT; ++t)
#pragma unroll
        for (int i = 0; i < 4; ++i) {
            int rr = outRowBase + i;
            if (rr < N) Outb[(size_t)rr * 128 + t * 16 + m] = f2bf(acc[t][i] * di[i]);
        }
}

// ---- FUSED agg+gemm (R14: straight-line MLP gather) ----
// R13 post-mortem: runtime-bound j-loop kept only 2 loads in flight/wave ->
// latency-bound (VALUBusy 33%, HBM 24%, MfmaUtil 1%, all low = stall regime).
// R14: lane group g (of 4x16) owns slots [8g,8g+8). Slot indices preloaded
// with ONE ushort8 load per node (no ds_bpermute at all); 8 independent
// dwordx4 gathers per node issued back-to-back, OOB slots read row 0 (colp
// pad zeroed in k_csr) and are VALUE-masked. Covers 32 slots; wave-uniform
// rare tail (P(deg>32)~1.5e-4) handles the rest. deg/slot loads for all 4
// nodes hoisted ahead of the chain.
template <int M_>
__global__ __launch_bounds__(256) void k_agg_gemm(
        const unsigned short* __restrict__ hs, const int* __restrict__ deg,
        const unsigned short* __restrict__ colp, const float* __restrict__ bias,
        const unsigned short* __restrict__ Wt, unsigned short* __restrict__ Outb) {
    constexpr int K = 128;          // agg feature width and gemm K
    constexpr int NT = M_ / 64;     // col tiles per wave: 128->2, 64->1
    __shared__ __align__(16) unsigned short As[16][136];
    int tid = threadIdx.x;
    int lane = tid & 63, wave = tid >> 6;
    int tileBase = blockIdx.x * 16;
    int g = lane >> 4, c = lane & 15;
    const unsigned short* hc = hs + c * 8;
    int nodeB = tileBase + wave * 4;

    // per-lane bias slice (used by group 0 at write-out)
    float bv[8];
    {
        const float4* bp = (const float4*)(bias + c * 8);
        float4 b0 = bp[0], b1 = bp[1];
        bv[0] = b0.x; bv[1] = b0.y; bv[2] = b0.z; bv[3] = b0.w;
        bv[4] = b1.x; bv[5] = b1.y; bv[6] = b1.z; bv[7] = b1.w;
    }

    // hoisted per-node metadata: deg + this group's 8 slot indices
    int cnt[4];
    u16x8 sl[4];
#pragma unroll
    for (int t = 0; t < 4; ++t) cnt[t] = min(deg[nodeB + t], SLOTS);
#pragma unroll
    for (int t = 0; t < 4; ++t)
        sl[t] = *(const u16x8*)(colp + (size_t)(nodeB + t) * SLOTS + g * 8);

    unsigned int smk = (g == 0) ? 0xffffffffu : 0u;   // self-term mask

    // ---- agg phase: wave aggregates rows wave*4 .. wave*4+3 ----
#pragma unroll
    for (int t = 0; t < 4; ++t) {
        int r = wave * 4 + t;
        int node = nodeB + t;

        // self term (all groups load the row -- L1-hot -- only g0 keeps it)
        u32x4 sv = *(const u32x4*)(hc + (size_t)node * K);
        // 8 independent gathers covering slots 0..31
        u32x4 vv[8];
        unsigned int mk[8];
#pragma unroll
        for (int k2 = 0; k2 < 8; ++k2) {
            int slot = g * 8 + k2;
            mk[k2] = (slot < cnt[t]) ? 0xffffffffu : 0u;
            vv[k2] = *(const u32x4*)(hc + (size_t)(int)sl[t][k2] * K);
        }

        float acc[8];
#pragma unroll
        for (int k = 0; k < 4; ++k) {
            unsigned int xv = sv[k] & smk;
            acc[2 * k] = bflo(xv); acc[2 * k + 1] = bfhi(xv);
        }
#pragma unroll
        for (int k2 = 0; k2 < 8; ++k2) {
#pragma unroll
            for (int k = 0; k < 4; ++k) {
                unsigned int xv = vv[k2][k] & mk[k2];
                acc[2 * k] += bflo(xv); acc[2 * k + 1] += bfhi(xv);
            }
        }

        // rare tail: deg > 32 (wave-uniform branch)
        if (cnt[t] > 32) {
            int mi = (lane < cnt[t]) ? (int)colp[(size_t)node * SLOTS + lane] : 0;
            for (int j = 32; j < cnt[t]; j += 4) {
                int i0 = __shfl(mi, j + g, 64);
                u32x4 v0 = {0, 0, 0, 0};
                if (j + g < cnt[t]) v0 = *(const u32x4*)(hc + (size_t)i0 * K);
#pragma unroll
                for (int k = 0; k < 4; ++k) {
                    acc[2 * k] += bflo(v0[k]); acc[2 * k + 1] += bfhi(v0[k]);
                }
            }
        }

        // cross-group reduce: groups {0,1,2,3} hold partial sums of same dims
#pragma unroll
        for (int k = 0; k < 8; ++k) {
            acc[k] += __shfl_xor(acc[k], 16, 64);
            acc[k] += __shfl_xor(acc[k], 32, 64);
        }
        if (g == 0) {
            float di = rsqrtf((float)cnt[t] + 1.0f);
            u32x4 pv;
#pragma unroll
            for (int k = 0; k < 4; ++k) {
                float o0 = fmaxf(di * acc[2 * k]     + bv[2 * k],     0.f);
                float o1 = fmaxf(di * acc[2 * k + 1] + bv[2 * k + 1], 0.f);
                pv[k] = (unsigned int)f2bf(o0) | ((unsigned int)f2bf(o1) << 16);
            }
            *(u32x4*)&As[r][c * 8] = pv;   // 16B aligned: 136*2*r % 16 == 0
        }
    }
    __syncthreads();

    // ---- gemm phase: 16 rows x M_ cols from LDS A-tile ----
    int m = lane & 15, quad = lane >> 4;
    bf16x8 afr[4];
#pragma unroll
    for (int s = 0; s < 4; ++s)
        afr[s] = *(const bf16x8*)&As[m][s * 32 + quad * 8];

    f32x4 gacc[NT];
#pragma unroll
    for (int t = 0; t < NT; ++t) { gacc[t][0] = 0.f; gacc[t][1] = 0.f; gacc[t][2] = 0.f; gacc[t][3] = 0.f; }
#pragma unroll
    for (int t = 0; t < NT; ++t) {
        int ct = wave * NT + t;     // col tile 0..M_/16-1
        const unsigned short* wp = Wt + (size_t)(ct * 16 + m) * K + quad * 8;
#pragma unroll
        for (int s = 0; s < 4; ++s) {
            bf16x8 bfr = *(const bf16x8*)(wp + s * 32);
            gacc[t] = __builtin_amdgcn_mfma_f32_16x16x32_bf16(afr[s], bfr, gacc[t], 0, 0, 0);
        }
    }

    int rowBase = tileBase + quad * 4;
    float di[4];
#pragma unroll
    for (int i = 0; i < 4; ++i) di[i] = rsqrtf((float)deg[rowBase + i] + 1.0f);
#pragma unroll
    for (int t = 0; t < NT; ++t) {
        int ct = wave * NT + t;
#pragma unroll
        for (int i = 0; i < 4; ++i)
            Outb[(size_t)(rowBase + i) * M_ + ct * 16 + m] = f2bf(gacc[t][i] * di[i]);
    }
}

// ---- final aggregation (F=64, no relu) -> z (bf16) ----
// R14: 8 groups of 8 lanes; 8 straight-line gathers cover ALL 64 slots --
// zero loops, zero shuffles for indices. Slot list preloaded as one ushort8.
__global__ __launch_bounds__(256) void k_agg64(
        const unsigned short* __restrict__ hs, const int* __restrict__ deg,
        const unsigned short* __restrict__ colp, const float* __restrict__ bias,
        unsigned short* __restrict__ out, int n) {
    int tid = threadIdx.x;
    int wave = tid >> 6, lane = tid & 63;
    int node = blockIdx.x * 4 + wave;               // grid exactly 12500
    int g = lane >> 3, c = lane & 7;
    const unsigned short* hc = hs + c * 8;

    int cnt = min(deg[node], SLOTS);
    u16x8 sl = *(const u16x8*)(colp + (size_t)node * SLOTS + g * 8);

    u32x4 sv = *(const u32x4*)(hc + (size_t)node * 64);
    u32x4 vv[8];
    unsigned int mk[8];
#pragma unroll
    for (int k2 = 0; k2 < 8; ++k2) {
        int slot = g * 8 + k2;
        mk[k2] = (slot < cnt) ? 0xffffffffu : 0u;
        vv[k2] = *(const u32x4*)(hc + (size_t)(int)sl[k2] * 64);
    }

    unsigned int smk = (g == 0) ? 0xffffffffu : 0u;
    float acc[8];
#pragma unroll
    for (int k = 0; k < 4; ++k) {
        unsigned int xv = sv[k] & smk;
        acc[2 * k] = bflo(xv); acc[2 * k + 1] = bfhi(xv);
    }
#pragma unroll
    for (int k2 = 0; k2 < 8; ++k2) {
#pragma unroll
        for (int k = 0; k < 4; ++k) {
            unsigned int xv = vv[k2][k] & mk[k2];
            acc[2 * k] += bflo(xv); acc[2 * k + 1] += bfhi(xv);
        }
    }
#pragma unroll
    for (int k = 0; k < 8; ++k) {
        acc[k] += __shfl_xor(acc[k], 8, 64);
        acc[k] += __shfl_xor(acc[k], 16, 64);
        acc[k] += __shfl_xor(acc[k], 32, 64);
    }
    if (g == 0) {
        float di = rsqrtf((float)cnt + 1.0f);
        const float4* bp = (const float4*)(bias + c * 8);
        float4 b0 = bp[0], b1 = bp[1];
        float bb[8] = {b0.x, b0.y, b0.z, b0.w, b1.x, b1.y, b1.z, b1.w};
        u32x4 pv;
#pragma unroll
        for (int k = 0; k < 4; ++k) {
            float o0 = di * acc[2 * k]     + bb[2 * k];
            float o1 = di * acc[2 * k + 1] + bb[2 * k + 1];
            pv[k] = (unsigned int)f2bf(o0) | ((unsigned int)f2bf(o1) << 16);
        }
        *(u32x4*)(out + (size_t)node * 64 + c * 8) = pv;
    }
}

// ---- decode: out[e] = dot(z[ls[e]], z[ld[e]]) over 64 dims, z bf16 ----
__global__ __launch_bounds__(256) void k_decode(
        const unsigned short* __restrict__ z, const int* __restrict__ ls,
        const int* __restrict__ ld, float* __restrict__ out, int nl) {
    int tid = threadIdx.x;
    int lane = tid & 63, wave = tid >> 6;
    int g = lane >> 3, c = lane & 7;
    int e = (blockIdx.x * 4 + wave) * 4 + (g >> 1);   // grid exactly 6250
    int row = (g & 1) ? ld[e] : ls[e];
    u32x4 v = *(const u32x4*)(z + (size_t)row * 64 + c * 8);
    u32x4 w;
#pragma unroll
    for (int k = 0; k < 4; ++k) w[k] = (unsigned int)__shfl_xor((int)v[k], 8, 64);
    float p = 0.f;
#pragma unroll
    for (int k = 0; k < 4; ++k)
        p += bflo(v[k]) * bflo(w[k]) + bfhi(v[k]) * bfhi(w[k]);
    p += __shfl_xor(p, 1, 64);
    p += __shfl_xor(p, 2, 64);
    p += __shfl_xor(p, 4, 64);
    if ((lane & 15) == 0) out[e] = p;   // lane in {0,16,32,48}: g even, c==0
}

// ================= launcher =================

static inline size_t align256(size_t x) { return (x + 255) & ~(size_t)255; }

extern "C" void kernel_launch(void* const* d_in, const int* in_sizes, int n_in,
                              void* d_out, int out_size, void* d_ws, size_t ws_size,
                              hipStream_t stream) {
    const float* x  = (const float*)d_in[0];
    const int*   ei = (const int*)d_in[1];    // [2][NE]: row0=src, row1=dst
    const int*   li = (const int*)d_in[2];    // [2][NL]
    const float* W1 = (const float*)d_in[3];
    const float* b1 = (const float*)d_in[4];
    const float* W2 = (const float*)d_in[5];
    const float* b2 = (const float*)d_in[6];
    const float* W3 = (const float*)d_in[7];
    const float* b3 = (const float*)d_in[8];
    float* out = (float*)d_out;

    const int* src = ei;
    const int* dst = ei + NE;
    const int* ls = li;
    const int* ld = li + NL;

    // workspace carve-up (~37 MB)
    char* ws = (char*)d_ws;
    size_t off = 0;
    int* deg    = (int*)(ws + off); off += align256(NN * 4);
    int* cursor = (int*)(ws + off); off += align256(NB * 4);
    unsigned int* binbuf = (unsigned int*)(ws + off); off += align256((size_t)NB * BCAP * 4);
    unsigned short* colp = (unsigned short*)(ws + off); off += align256((size_t)NN * SLOTS * 2);
    unsigned short* Wtb  = (unsigned short*)(ws + off); off += align256(40960 * 2);
    unsigned short* bufA = (unsigned short*)(ws + off); off += align256((size_t)NN * 128 * 2);
    unsigned short* bufB = (unsigned short*)(ws + off); off += align256((size_t)NN * 128 * 2);
    unsigned short* bufZ = (unsigned short*)(ws + off); off += align256((size_t)NN * 64 * 2);

    // ---- CSR build + W prep ----
    k_wprep<<<160, 256, 0, stream>>>(W1, W2, W3, Wtb, cursor);
    k_bin<<<391, 256, 0, stream>>>(src, dst, cursor, binbuf);
    k_csr<<<NB, 256, 0, stream>>>(binbuf, cursor, deg, colp);

    // ---- layer 1 GEMM: x -> bufA (h1 = dinv * x@W1, bf16) ----
    k_gemm1<<<782, 256, 0, stream>>>(x, Wtb, deg, bufA, NN);
    // ---- fused agg1(+b1,relu) + gemm2: bufA -> bufB (h2) ----
    k_agg_gemm<128><<<3125, 256, 0, stream>>>(bufA, deg, colp, b1, Wtb + 16384, bufB);
    // ---- fused agg2(+b2,relu) + gemm3: bufB -> bufA (h3, 64-wide) ----
    k_agg_gemm<64><<<3125, 256, 0, stream>>>(bufB, deg, colp, b2, Wtb + 32768, bufA);
    // ---- agg3(+b3, no relu): bufA -> bufZ (z) ----
    k_agg64<<<12500, 256, 0, stream>>>(bufA, deg, colp, b3, bufZ, NN);
    // ---- decode ----
    k_decode<<<6250, 256, 0, stream>>>(bufZ, ls, ld, out, NL);
}